// Round 15
// baseline (83.463 us; speedup 1.0000x reference)
//
#include <hip/hip_runtime.h>

#define BB 8
#define TT 256
#define UU 64
#define VV 512
#define U1 (UU + 1)
#define NDG 90                  // diagonal groups per batch (81 used + prefetch pad)
#define NEG (-1e30f)

#define LOG2E 1.4426950408889634f
#define LN2   0.6931471805599453f
#define NEG_INF (-__builtin_inff())

typedef float floatx4 __attribute__((ext_vector_type(4)));

__device__ __forceinline__ float vexp2(float x) {
    float r; asm("v_exp_f32 %0, %1" : "=v"(r) : "v"(x)); return r;
}
__device__ __forceinline__ float vlog2(float x) {
    float r; asm("v_log_f32 %0, %1" : "=v"(r) : "v"(x)); return r;
}
__device__ __forceinline__ float negabs(float x) {
    return __int_as_float(__float_as_int(x) | 0x80000000u);
}
__device__ __forceinline__ float rdlane63(float x) {
    return __int_as_float(__builtin_amdgcn_readlane(__float_as_int(x), 63));
}

template<int CTRL, int RMASK>
__device__ __forceinline__ float dpp_mov(float v, float oldv) {
    int r = __builtin_amdgcn_update_dpp(__float_as_int(oldv), __float_as_int(v),
                                        CTRL, RMASK, 0xf, false);
    return __int_as_float(r);
}

__device__ __forceinline__ float wave_addscan(float v) {
    v += dpp_mov<0x111, 0xf>(v, 0.f);
    v += dpp_mov<0x112, 0xf>(v, 0.f);
    v += dpp_mov<0x114, 0xf>(v, 0.f);
    v += dpp_mov<0x118, 0xf>(v, 0.f);
    v += dpp_mov<0x142, 0xa>(v, 0.f);
    v += dpp_mov<0x143, 0xc>(v, 0.f);
    return v;
}
__device__ __forceinline__ float wave_maxscan(float v) {
    v = fmaxf(v, dpp_mov<0x111, 0xf>(v, NEG_INF));
    v = fmaxf(v, dpp_mov<0x112, 0xf>(v, NEG_INF));
    v = fmaxf(v, dpp_mov<0x114, 0xf>(v, NEG_INF));
    v = fmaxf(v, dpp_mov<0x118, 0xf>(v, NEG_INF));
    v = fmaxf(v, dpp_mov<0x142, 0xa>(v, NEG_INF));
    v = fmaxf(v, dpp_mov<0x143, 0xc>(v, NEG_INF));
    return v;
}

// Kernel 1 (fused): zero out[0]; per-row log-softmax; scatter blank/emit lp
// (log2 domain) into diagonal-major arrays. Dead rows scatter NEG. Cells never
// covered by any row (t<0 / t>=256) keep harness poison; the scan masks the
// d<l emit strip and d<64 side strip (the only pre-latch-reachable poison).
__global__ __launch_bounds__(256) void k_logsm(const float* __restrict__ logits,
                                               const int* __restrict__ targets,
                                               const int* __restrict__ loglen,
                                               const int* __restrict__ tgtlen,
                                               float* __restrict__ Bd4,
                                               float* __restrict__ Ed4,
                                               float* __restrict__ B64,
                                               float* __restrict__ E64,
                                               float* __restrict__ out) {
    if (blockIdx.x == 0 && threadIdx.x == 0) out[0] = 0.f;
    int wave = (int)((blockIdx.x * blockDim.x + threadIdx.x) >> 6);
    int lane = threadIdx.x & 63;
    const int nrows = BB * TT * U1;
    if (wave >= nrows) return;
    int u  = wave % U1;
    int bt = wave / U1;
    int b  = bt / TT;
    int t  = bt - b * TT;
    int d  = t + u + 1;

    if (t >= loglen[b] || u > tgtlen[b]) {         // dead row: scatter NEG, no loads
        if (lane == 0) {
            if (u < 64) Bd4[((b * NDG + (d >> 2)) * 64 + u) * 4 + (d & 3)] = NEG;
            else        B64[b * (NDG * 4) + (t + 65)] = NEG;
            if (u < 63)      Ed4[((b * NDG + (d >> 2)) * 64 + (u + 1)) * 4 + (d & 3)] = NEG;
            else if (u == 63) E64[b * (NDG * 4) + (t + 64)] = NEG;
        }
        return;
    }

    const float* row = logits + (size_t)wave * VV;
    floatx4 v0 = __builtin_nontemporal_load((const floatx4*)(row + lane * 4));
    floatx4 v1 = __builtin_nontemporal_load((const floatx4*)(row + 256 + lane * 4));
    float m8 = fmaxf(fmaxf(fmaxf(v0.x, v0.y), fmaxf(v0.z, v0.w)),
                     fmaxf(fmaxf(v1.x, v1.y), fmaxf(v1.z, v1.w)));
    float M = rdlane63(wave_maxscan(m8));
    float s8 = __expf(v0.x - M) + __expf(v0.y - M) + __expf(v0.z - M) + __expf(v0.w - M)
             + __expf(v1.x - M) + __expf(v1.y - M) + __expf(v1.z - M) + __expf(v1.w - M);
    float S = rdlane63(wave_addscan(s8));
    float lse = M + __logf(S);

    if (lane == 0) {
        float blv = (v0.x - lse) * LOG2E;          // blank lp, log2 domain
        if (u < 64) Bd4[((b * NDG + (d >> 2)) * 64 + u) * 4 + (d & 3)] = blv;
        else        B64[b * (NDG * 4) + (t + 65)] = blv;
    }
    if (u < UU) {
        int tgt = targets[b * UU + u];             // in [1, V)
        int owner = (tgt & 255) >> 2;
        if (lane == owner) {
            int slot = tgt & 3;
            float x0 = (tgt < 256) ? v0.x : v1.x;
            float x1 = (tgt < 256) ? v0.y : v1.y;
            float x2 = (tgt < 256) ? v0.z : v1.z;
            float x3 = (tgt < 256) ? v0.w : v1.w;
            float val = (slot == 0) ? x0 : (slot == 1) ? x1 : (slot == 2) ? x2 : x3;
            float em = (val - lse) * LOG2E;        // emit lp, log2 domain
            if (u < 63) Ed4[((b * NDG + (d >> 2)) * 64 + (u + 1)) * 4 + (d & 3)] = em;
            else        E64[b * (NDG * 4) + (t + 64)] = em;
        }
    }
}

struct Grp { floatx4 vb, ve, vb6, ve6; };

// Kernel 2: anti-diagonal alpha recursion, 6-buffer rotation, distance-5
// prefetch. After slot d, lane l holds alpha[d-l][l] as (m,s): a = m + log2(s).
__global__ __launch_bounds__(64) void k_scan(const float* __restrict__ Bd4,
                                             const float* __restrict__ Ed4,
                                             const float* __restrict__ B64,
                                             const float* __restrict__ E64,
                                             const int* __restrict__ loglen,
                                             const int* __restrict__ tgtlen,
                                             float* __restrict__ out) {
    int b = blockIdx.x;
    int l = threadIdx.x;
    int t_idx = loglen[b] - 1;
    int u_idx = tgtlen[b];
    int d_fin = t_idx + u_idx;                    // latch alpha here; +1 latches blank
    const bool need64 = (u_idx == 64);
    const bool rec_main = (l == u_idx);
    const bool rec_side = need64 && (l == 63);

    const float* pB  = Bd4 + (size_t)b * NDG * 256 + l * 4;
    const float* pE  = Ed4 + (size_t)b * NDG * 256 + l * 4;
    const float* p6B = B64 + b * (NDG * 4);
    const float* p6E = E64 + b * (NDG * 4);

    int paddr = (l - 1) << 2;
    bool lane0 = (l == 0);

    float Am = lane0 ? 0.f : NEG, As = 1.f;       // alpha[0][0]=0 at slot 0
    float A64m = NEG, A64s = 1.f;
    float gm = NEG, gs = 1.f, fb = 0.f;

    Grp G0, G1, G2, G3, G4, G5;

#define LOADG(G, g_) do { int gg = (g_);                                         \
        G.vb  = *(const floatx4*)(pB  + gg * 256);                               \
        G.ve  = *(const floatx4*)(pE  + gg * 256);                               \
        G.vb6 = *(const floatx4*)(p6B + gg * 4);                                 \
        G.ve6 = *(const floatx4*)(p6E + gg * 4);                                 \
    } while (0)

#define STEP1(bv, ev, b64v, e64v, dd) do { int d_ = (dd);                        \
        float pm = __int_as_float(__builtin_amdgcn_ds_bpermute(paddr,            \
                                   __float_as_int(Am)));                         \
        float ps = __int_as_float(__builtin_amdgcn_ds_bpermute(paddr,            \
                                   __float_as_int(As)));                         \
        pm = lane0 ? NEG : pm;                                                   \
        ps = lane0 ? 1.f : ps;                                                   \
        float preAm = Am, preAs = As;   /* lane-local pre-slot state */          \
        float ma = Am + (bv);                                                    \
        float me = (d_ >= l) ? (pm + (ev)) : NEG;  /* mask t<0 poison strip */   \
        bool c = ma >= me;                                                       \
        float M = fmaxf(ma, me);                                                 \
        float w = vexp2(negabs(ma - me));                                        \
        float bg = c ? As : ps, sm = c ? ps : As;                                \
        float S = fmaf(sm, w, bg);                                               \
        if (need64) {                                                            \
            float sa = A64m + (b64v);                                            \
            float se = (d_ >= 64) ? (preAm + (e64v)) : NEG;                      \
            bool c2 = sa >= se;                                                  \
            float M2 = fmaxf(sa, se);                                            \
            float w2 = vexp2(negabs(sa - se));                                   \
            float bg2 = c2 ? A64s : preAs, sm2 = c2 ? preAs : A64s;              \
            A64s = fmaf(sm2, w2, bg2); A64m = M2;                                \
        }                                                                        \
        Am = M; As = S;                                                          \
        bool hit0 = (d_ == d_fin), hit1 = (d_ == d_fin + 1);                     \
        bool h0m = hit0 && rec_main, h1m = hit1 && rec_main;                     \
        gm = h0m ? M : gm;  gs = h0m ? S : gs;  fb = h1m ? (bv) : fb;            \
        if (need64) {                                                            \
            bool h0s = hit0 && rec_side, h1s = hit1 && rec_side;                 \
            gm = h0s ? A64m : gm; gs = h0s ? A64s : gs;                          \
            fb = h1s ? (b64v) : fb;                                              \
        }                                                                        \
    } while (0)

#define RENORM do {                                                              \
        int e1; As = frexpf(As, &e1); Am += (float)e1;                           \
        if (need64) { int e2; A64s = frexpf(A64s, &e2); A64m += (float)e2; }     \
    } while (0)

#define STEP4(G, g_) do { int gq = (g_);                                         \
        STEP1(G.vb.x, G.ve.x, G.vb6.x, G.ve6.x, 4 * gq + 0);                     \
        STEP1(G.vb.y, G.ve.y, G.vb6.y, G.ve6.y, 4 * gq + 1);                     \
        STEP1(G.vb.z, G.ve.z, G.vb6.z, G.ve6.z, 4 * gq + 2);                     \
        STEP1(G.vb.w, G.ve.w, G.vb6.w, G.ve6.w, 4 * gq + 3);                     \
        RENORM;                                                                  \
    } while (0)

    LOADG(G0, 0); LOADG(G1, 1); LOADG(G2, 2);
    LOADG(G3, 3); LOADG(G4, 4); LOADG(G5, 5);

    // slots 0..323; slot 0 is numerically inert (poison arms masked/tiny).
    for (int cc = 0; cc < 13; ++cc) {
        int base = 6 * cc;
        STEP4(G0, base + 0); LOADG(G0, base + 6);
        STEP4(G1, base + 1); LOADG(G1, base + 7);
        STEP4(G2, base + 2); LOADG(G2, base + 8);
        STEP4(G3, base + 3); LOADG(G3, base + 9);
        STEP4(G4, base + 4); LOADG(G4, base + 10);
        STEP4(G5, base + 5); LOADG(G5, base + 11);
    }
    STEP4(G0, 78); STEP4(G1, 79); STEP4(G2, 80);

    int wl = need64 ? 63 : u_idx;
    if (l == wl) {
        float g = gm + vlog2(gs);
        atomicAdd(out, -0.125f * (g + fb) * LN2);
    }
#undef LOADG
#undef STEP1
#undef RENORM
#undef STEP4
}

extern "C" void kernel_launch(void* const* d_in, const int* in_sizes, int n_in,
                              void* d_out, int out_size, void* d_ws, size_t ws_size,
                              hipStream_t stream) {
    const float* logits  = (const float*)d_in[0];
    const int*   targets = (const int*)d_in[1];
    const int*   loglen  = (const int*)d_in[2];
    const int*   tgtlen  = (const int*)d_in[3];

    float* ws  = (float*)d_ws;
    float* Bd4 = ws;                               // 8*90*256 = 184320
    float* Ed4 = Bd4 + BB * NDG * 256;             // 184320
    float* B64 = Ed4 + BB * NDG * 256;             // 8*360 = 2880
    float* E64 = B64 + BB * (NDG * 4);             // 2880

    const int nrows = BB * TT * U1;
    k_logsm<<<nrows / 4, 256, 0, stream>>>(logits, targets, loglen, tgtlen,
                                           Bd4, Ed4, B64, E64, (float*)d_out);
    k_scan<<<BB, 64, 0, stream>>>(Bd4, Ed4, B64, E64, loglen, tgtlen, (float*)d_out);
}